// Round 11
// baseline (242.006 us; speedup 1.0000x reference)
//
#include <hip/hip_runtime.h>
#include <hip/hip_bf16.h>

// Problem: B=8, T=1024, C=768, H=12, HD=64. M = 8192. fp32 in/out.
// R11: attn load-balancing — block pi handles query tiles (pi, 7-pi): every
// block = 18 tile-iters of MFMA (tail eliminated; R10 had 2..16 iters/block,
// Occupancy 16%). V stored transposed [B,H,D,T] at qkv epilogue -> attn V
// staging is a vectorized row copy (R10's scalar LDS transpose = most of the
// 4.03e6 conflict cycles). Q frags read directly from global (no Q staging).
// GEMMs + casts otherwise unchanged from R8/R10 (verified).

#define TDIM 1024
#define CDIM 768
#define NDIM 2304

typedef __attribute__((ext_vector_type(8))) short bf16x8;
typedef __attribute__((ext_vector_type(8))) unsigned short u16x8;
typedef __attribute__((ext_vector_type(4))) float f32x4;

__device__ __forceinline__ unsigned short f2bf(float f) {
    unsigned int u;
    __builtin_memcpy(&u, &f, 4);
    u += 0x7FFFu + ((u >> 16) & 1u);  // RNE
    return (unsigned short)(u >> 16);
}

__device__ __forceinline__ void async_copy16(void* lds, const void* g) {
    __builtin_amdgcn_global_load_lds(
        (const __attribute__((address_space(1))) void*)g,
        (__attribute__((address_space(3))) void*)lds, 16, 0, 0);
}

// ---------------------------------------------------------------------------
// Precast kernels.
// ---------------------------------------------------------------------------
__global__ __launch_bounds__(256) void cast_x(const float* __restrict__ x,
                                              unsigned short* __restrict__ xb) {
    const size_t i = ((size_t)blockIdx.x * 256 + threadIdx.x) * 4;
    float4 v = *(const float4*)&x[i];
    ushort4 s;
    s.x = f2bf(v.x); s.y = f2bf(v.y); s.z = f2bf(v.z); s.w = f2bf(v.w);
    *(ushort4*)&xb[i] = s;
}

template <int N>
__global__ __launch_bounds__(256) void transpose_cast(const float* __restrict__ W,
                                                      unsigned short* __restrict__ Wt) {
    __shared__ float tile[32][33];
    const int n0 = blockIdx.x * 32;
    const int k0 = blockIdx.y * 32;
    const int tx = threadIdx.x & 31;
    const int ty = threadIdx.x >> 5;
#pragma unroll
    for (int i = 0; i < 4; ++i)
        tile[ty + i * 8][tx] = W[(size_t)(k0 + ty + i * 8) * N + n0 + tx];
    __syncthreads();
#pragma unroll
    for (int i = 0; i < 4; ++i)
        Wt[(size_t)(n0 + ty + i * 8) * CDIM + k0 + tx] = f2bf(tile[tx][ty + i * 8]);
}

// ---------------------------------------------------------------------------
// Kernel 1: qkv GEMM (m97 structure). Q/K scatter as before; V written
// TRANSPOSED [B,H,D,T] with t-contiguous ushort4 stores.
// ---------------------------------------------------------------------------
__global__ __launch_bounds__(256) void qkv_mfma(
    const unsigned short* __restrict__ xb, const unsigned short* __restrict__ Wt,
    const float* __restrict__ bias,
    unsigned short* __restrict__ Q, unsigned short* __restrict__ Kd,
    unsigned short* __restrict__ Vt)
{
    const int n0 = blockIdx.x * 128;
    const int m0 = blockIdx.y * 128;
    const int tid = threadIdx.x;
    const int lane = tid & 63;
    const int w = tid >> 6;
    const int wm = w & 1;
    const int wn = w >> 1;
    const int lm = lane & 15;
    const int lq = lane >> 4;

    __shared__ __align__(16) unsigned short As[128 * 32];
    __shared__ __align__(16) unsigned short Bs[128 * 32];

    f32x4 acc[4][4] = {};

    const int srow = lane >> 2;
    const int schunk = lane & 3;

    for (int k0 = 0; k0 < CDIM; k0 += 32) {
        __syncthreads();
#pragma unroll
        for (int c = 0; c < 2; ++c) {
            const int rbase = c * 64 + w * 16;
            async_copy16(&As[rbase * 32],
                         &xb[(size_t)(m0 + rbase + srow) * CDIM + k0 + schunk * 8]);
            async_copy16(&Bs[rbase * 32],
                         &Wt[(size_t)(n0 + rbase + srow) * CDIM + k0 + schunk * 8]);
        }
        __syncthreads();

        bf16x8 a[4], b[4];
#pragma unroll
        for (int mi = 0; mi < 4; ++mi)
            a[mi] = *(const bf16x8*)&As[(wm * 64 + mi * 16 + lm) * 32 + lq * 8];
#pragma unroll
        for (int ni = 0; ni < 4; ++ni)
            b[ni] = *(const bf16x8*)&Bs[(wn * 64 + ni * 16 + lm) * 32 + lq * 8];
#pragma unroll
        for (int mi = 0; mi < 4; ++mi)
#pragma unroll
            for (int ni = 0; ni < 4; ++ni)
                acc[mi][ni] = __builtin_amdgcn_mfma_f32_16x16x32_bf16(
                    a[mi], b[ni], acc[mi][ni], 0, 0, 0);
    }

#pragma unroll
    for (int ni = 0; ni < 4; ++ni) {
        const int gn = n0 + wn * 64 + ni * 16 + lm;
        const float bb = bias[gn];
        const int h = gn / 192;
        const int rr = gn % 192;
        const int which = rr >> 6;
        const int d = rr & 63;
        if (which == 2) {
            // V transposed: [B,H,D,T], 4 t-contiguous values per mi.
#pragma unroll
            for (int mi = 0; mi < 4; ++mi) {
                const int gm0 = m0 + wm * 64 + mi * 16 + lq * 4;
                const int bidx = gm0 >> 10;
                const int t0 = gm0 & 1023;
                ushort4 sv;
                sv.x = f2bf(acc[mi][ni][0] + bb);
                sv.y = f2bf(acc[mi][ni][1] + bb);
                sv.z = f2bf(acc[mi][ni][2] + bb);
                sv.w = f2bf(acc[mi][ni][3] + bb);
                *(ushort4*)&Vt[(((size_t)bidx * 12 + h) * 64 + d) * TDIM + t0] = sv;
            }
        } else {
            unsigned short* dst = (which == 0) ? Q : Kd;
#pragma unroll
            for (int mi = 0; mi < 4; ++mi) {
#pragma unroll
                for (int r = 0; r < 4; ++r) {
                    const int gm = m0 + wm * 64 + mi * 16 + lq * 4 + r;
                    const int bidx = gm >> 10;
                    const int t = gm & 1023;
                    dst[(((size_t)bidx * 12 + h) * TDIM + t) * 64 + d] = f2bf(acc[mi][ni][r] + bb);
                }
            }
        }
    }
}

// ---------------------------------------------------------------------------
// Kernel 2: MFMA causal flash attention v3 — paired query tiles (pi, 7-pi),
// shift-free softmax. grid = (4, 96), block = 256 (4 waves); wave owns 32
// queries of each tile. V pre-transposed in global.
// ---------------------------------------------------------------------------
#define ATTN_TILE(aq, q0t, l_p, o, diagflag) do {                               \
    const bool diag_ = (diagflag);                                              \
    _Pragma("unroll")                                                           \
    for (int mt = 0; mt < 2; ++mt) {                                            \
        float pf[4][4];                                                         \
        _Pragma("unroll")                                                       \
        for (int nt = 0; nt < 4; ++nt) {                                        \
            f32x4 s = {};                                                       \
            _Pragma("unroll")                                                   \
            for (int kc = 0; kc < 2; ++kc) {                                    \
                bf16x8 bfrag = *(const bf16x8*)&Ks[nt * 16 + lm][kc * 32 + lq * 8]; \
                s = __builtin_amdgcn_mfma_f32_16x16x32_bf16(aq[mt][kc], bfrag, s, 0, 0, 0); \
            }                                                                   \
            const int keyg = kbase + nt * 16 + lm;                              \
            _Pragma("unroll")                                                   \
            for (int r = 0; r < 4; ++r) {                                       \
                float p = __builtin_amdgcn_exp2f(s[r] * SC);                    \
                if (diag_) {                                                    \
                    const int qg = (q0t) + w * 32 + mt * 16 + lq * 4 + r;       \
                    if (keyg > qg) p = 0.f;                                     \
                }                                                               \
                pf[nt][r] = p;                                                  \
            }                                                                   \
        }                                                                       \
        _Pragma("unroll")                                                       \
        for (int r = 0; r < 4; ++r) {                                           \
            l_p[mt][r] += pf[0][r] + pf[1][r] + pf[2][r] + pf[3][r];            \
            _Pragma("unroll")                                                   \
            for (int nt = 0; nt < 4; ++nt)                                      \
                Ps[w][mt * 16 + lq * 4 + r][nt * 16 + lm] = f2bf(pf[nt][r]);    \
        }                                                                       \
    }                                                                           \
    _Pragma("unroll")                                                           \
    for (int mt = 0; mt < 2; ++mt) {                                            \
        bf16x8 ap[2];                                                           \
        _Pragma("unroll")                                                       \
        for (int kc = 0; kc < 2; ++kc)                                          \
            ap[kc] = *(const bf16x8*)&Ps[w][mt * 16 + lm][kc * 32 + lq * 8];    \
        _Pragma("unroll")                                                       \
        for (int nt = 0; nt < 4; ++nt) {                                        \
            _Pragma("unroll")                                                   \
            for (int kc = 0; kc < 2; ++kc) {                                    \
                bf16x8 bv = *(const bf16x8*)&Vts[nt * 16 + lm][kc * 32 + lq * 8]; \
                o[mt][nt] = __builtin_amdgcn_mfma_f32_16x16x32_bf16(ap[kc], bv, o[mt][nt], 0, 0, 0); \
            }                                                                   \
        }                                                                       \
    }                                                                           \
} while (0)

#define ATTN_EPI(q0t, l_p, o) do {                                              \
    _Pragma("unroll")                                                           \
    for (int mt = 0; mt < 2; ++mt)                                              \
        _Pragma("unroll")                                                       \
        for (int r = 0; r < 4; ++r) {                                           \
            float l = l_p[mt][r];                                               \
            _Pragma("unroll")                                                   \
            for (int off = 1; off < 16; off <<= 1) l += __shfl_xor(l, off);     \
            const float inv = 1.0f / l;                                         \
            const int qg = (q0t) + w * 32 + mt * 16 + lq * 4 + r;               \
            _Pragma("unroll")                                                   \
            for (int nt = 0; nt < 4; ++nt)                                      \
                Yb[(size_t)qg * 64 + nt * 16 + lm] = f2bf(o[mt][nt][r] * inv);  \
        }                                                                       \
} while (0)

__global__ __launch_bounds__(256) void attn_mfma(
    const unsigned short* __restrict__ Q, const unsigned short* __restrict__ K,
    const unsigned short* __restrict__ Vt, unsigned short* __restrict__ Y)
{
    const int pi = blockIdx.x;        // 0..3 -> tiles (pi, 7-pi)
    const int bh = blockIdx.y;        // 0..95
    const int qtA = pi, qtB = 7 - pi;
    const int q0A = qtA * 128, q0B = qtB * 128;
    const int tid = threadIdx.x;
    const int lane = tid & 63;
    const int w = tid >> 6;
    const int lm = lane & 15;
    const int lq = lane >> 4;

    __shared__ __align__(16) unsigned short Ks[64][72];
    __shared__ __align__(16) unsigned short Vts[64][72];   // [d][key]
    __shared__ __align__(16) unsigned short Ps[4][32][72];

    const unsigned short* Qb = Q + (size_t)bh * TDIM * 64;
    const unsigned short* Kb = K + (size_t)bh * TDIM * 64;
    const unsigned short* Vtb = Vt + (size_t)bh * 64 * TDIM;
    unsigned short* Yb = Y + (size_t)bh * TDIM * 64;

    // Q fragments directly from global (once per kernel).
    bf16x8 aqA[2][2], aqB[2][2];
#pragma unroll
    for (int mt = 0; mt < 2; ++mt)
#pragma unroll
        for (int kc = 0; kc < 2; ++kc) {
            aqA[mt][kc] = *(const bf16x8*)&Qb[(size_t)(q0A + w * 32 + mt * 16 + lm) * 64 + kc * 32 + lq * 8];
            aqB[mt][kc] = *(const bf16x8*)&Qb[(size_t)(q0B + w * 32 + mt * 16 + lm) * 64 + kc * 32 + lq * 8];
        }

    float lA[2][4] = {}, lB[2][4] = {};
    f32x4 oA[2][4] = {}, oB[2][4] = {};

    const float SC = 0.125f * 1.44269504f;
    const int nktA = 2 * qtA + 2;
    const int nktB = 2 * qtB + 2;

    for (int kt = 0; kt < nktB; ++kt) {
        const int kbase = kt * 64;
        __syncthreads();
        // K tile rows + V^T tile rows (both vectorized 16B copies).
#pragma unroll
        for (int it = 0; it < 2; ++it) {
            const int idx = tid + it * 256;
            const int r = idx >> 3;
            const int c = idx & 7;
            *(u16x8*)&Ks[r][c * 8] =
                *(const u16x8*)&Kb[(size_t)(kbase + r) * 64 + c * 8];
            *(u16x8*)&Vts[r][c * 8] =
                *(const u16x8*)&Vtb[(size_t)r * TDIM + kbase + c * 8];
        }
        __syncthreads();

        ATTN_TILE(aqB, q0B, lB, oB, (kt >= 2 * qtB));
        if (kt < nktA) ATTN_TILE(aqA, q0A, lA, oA, (kt >= 2 * qtA));
    }

    ATTN_EPI(q0A, lA, oA);
    ATTN_EPI(q0B, lB, oB);
}

// ---------------------------------------------------------------------------
// Kernel 3: proj GEMM (m97 structure, unchanged from R8).
// ---------------------------------------------------------------------------
__global__ __launch_bounds__(256) void proj_mfma(
    const unsigned short* __restrict__ Y, const unsigned short* __restrict__ Wt,
    const float* __restrict__ bias, float* __restrict__ out)
{
    const int n0 = blockIdx.x * 128;
    const int m0 = blockIdx.y * 128;
    const int tid = threadIdx.x;
    const int lane = tid & 63;
    const int w = tid >> 6;
    const int wm = w & 1;
    const int wn = w >> 1;
    const int lm = lane & 15;
    const int lq = lane >> 4;

    __shared__ __align__(16) unsigned short As[128 * 32];
    __shared__ __align__(16) unsigned short Bs[128 * 32];

    f32x4 acc[4][4] = {};

    const int srow = lane >> 2;
    const int schunk = lane & 3;

    for (int k0 = 0; k0 < CDIM; k0 += 32) {
        const int h = k0 >> 6;
        const int inner = k0 & 63;
        __syncthreads();
#pragma unroll
        for (int c = 0; c < 2; ++c) {
            const int rbase = c * 64 + w * 16;
            const int m = m0 + rbase + srow;
            const int bidx = m >> 10;
            const int t = m & 1023;
            async_copy16(&As[rbase * 32],
                         &Y[(((size_t)bidx * 12 + h) * TDIM + t) * 64 + inner + schunk * 8]);
            async_copy16(&Bs[rbase * 32],
                         &Wt[(size_t)(n0 + rbase + srow) * CDIM + k0 + schunk * 8]);
        }
        __syncthreads();

        bf16x8 a[4], b[4];
#pragma unroll
        for (int mi = 0; mi < 4; ++mi)
            a[mi] = *(const bf16x8*)&As[(wm * 64 + mi * 16 + lm) * 32 + lq * 8];
#pragma unroll
        for (int ni = 0; ni < 4; ++ni)
            b[ni] = *(const bf16x8*)&Bs[(wn * 64 + ni * 16 + lm) * 32 + lq * 8];
#pragma unroll
        for (int mi = 0; mi < 4; ++mi)
#pragma unroll
            for (int ni = 0; ni < 4; ++ni)
                acc[mi][ni] = __builtin_amdgcn_mfma_f32_16x16x32_bf16(
                    a[mi], b[ni], acc[mi][ni], 0, 0, 0);
    }

#pragma unroll
    for (int ni = 0; ni < 4; ++ni) {
        const int gn = n0 + wn * 64 + ni * 16 + lm;
        const float bb = bias[gn];
#pragma unroll
        for (int mi = 0; mi < 4; ++mi) {
#pragma unroll
            for (int r = 0; r < 4; ++r) {
                const int gm = m0 + wm * 64 + mi * 16 + lq * 4 + r;
                out[(size_t)gm * CDIM + gn] = acc[mi][ni][r] + bb;
            }
        }
    }
}

extern "C" void kernel_launch(void* const* d_in, const int* in_sizes, int n_in,
                              void* d_out, int out_size, void* d_ws, size_t ws_size,
                              hipStream_t stream) {
    const float* x      = (const float*)d_in[0];
    const float* W_attn = (const float*)d_in[1];
    const float* b_attn = (const float*)d_in[2];
    const float* W_proj = (const float*)d_in[3];
    const float* b_proj = (const float*)d_in[4];
    float* out = (float*)d_out;

    const size_t per = (size_t)8 * 12 * 1024 * 64;
    unsigned short* Q   = (unsigned short*)d_ws;
    unsigned short* K   = Q + per;
    unsigned short* Vt  = K + per;   // [B,H,D,T] transposed
    unsigned short* xb  = Vt + per;
    unsigned short* Wta = xb + (size_t)8192 * CDIM;
    unsigned short* Wtp = Wta + (size_t)NDIM * CDIM;

    cast_x<<<dim3(6144), 256, 0, stream>>>(x, xb);
    transpose_cast<NDIM><<<dim3(72, 24), 256, 0, stream>>>(W_attn, Wta);
    transpose_cast<CDIM><<<dim3(24, 24), 256, 0, stream>>>(W_proj, Wtp);

    qkv_mfma<<<dim3(18, 64), 256, 0, stream>>>(xb, Wta, b_attn, Q, K, Vt);
    attn_mfma<<<dim3(4, 96), 256, 0, stream>>>(Q, K, Vt, Q);
    proj_mfma<<<dim3(6, 64), 256, 0, stream>>>(Q, Wtp, b_proj, out);
}

// Round 12
// 204.422 us; speedup vs baseline: 1.1839x; 1.1839x over previous
//
#include <hip/hip_runtime.h>
#include <hip/hip_bf16.h>

// Problem: B=8, T=1024, C=768, H=12, HD=64. M = 8192. fp32 in/out.
// R12: attn pairing at 64-query granularity — block pi handles tiles
// (pi, 15-pi): every block = 17 MFMA tile-units AND grid stays (8,96)=768
// blocks (R11's 384-block/140-VGPR regression fixed: one m-tile per tile
// halves accumulator state; A+B share each staged K/V tile).
// V stored transposed [B,H,D,T] at qkv epilogue (R11's conflict fix, kept).
// GEMMs + casts unchanged from R8 (verified).

#define TDIM 1024
#define CDIM 768
#define NDIM 2304

typedef __attribute__((ext_vector_type(8))) short bf16x8;
typedef __attribute__((ext_vector_type(8))) unsigned short u16x8;
typedef __attribute__((ext_vector_type(4))) float f32x4;

__device__ __forceinline__ unsigned short f2bf(float f) {
    unsigned int u;
    __builtin_memcpy(&u, &f, 4);
    u += 0x7FFFu + ((u >> 16) & 1u);  // RNE
    return (unsigned short)(u >> 16);
}

__device__ __forceinline__ void async_copy16(void* lds, const void* g) {
    __builtin_amdgcn_global_load_lds(
        (const __attribute__((address_space(1))) void*)g,
        (__attribute__((address_space(3))) void*)lds, 16, 0, 0);
}

// ---------------------------------------------------------------------------
// Precast kernels.
// ---------------------------------------------------------------------------
__global__ __launch_bounds__(256) void cast_x(const float* __restrict__ x,
                                              unsigned short* __restrict__ xb) {
    const size_t i = ((size_t)blockIdx.x * 256 + threadIdx.x) * 4;
    float4 v = *(const float4*)&x[i];
    ushort4 s;
    s.x = f2bf(v.x); s.y = f2bf(v.y); s.z = f2bf(v.z); s.w = f2bf(v.w);
    *(ushort4*)&xb[i] = s;
}

template <int N>
__global__ __launch_bounds__(256) void transpose_cast(const float* __restrict__ W,
                                                      unsigned short* __restrict__ Wt) {
    __shared__ float tile[32][33];
    const int n0 = blockIdx.x * 32;
    const int k0 = blockIdx.y * 32;
    const int tx = threadIdx.x & 31;
    const int ty = threadIdx.x >> 5;
#pragma unroll
    for (int i = 0; i < 4; ++i)
        tile[ty + i * 8][tx] = W[(size_t)(k0 + ty + i * 8) * N + n0 + tx];
    __syncthreads();
#pragma unroll
    for (int i = 0; i < 4; ++i)
        Wt[(size_t)(n0 + ty + i * 8) * CDIM + k0 + tx] = f2bf(tile[tx][ty + i * 8]);
}

// ---------------------------------------------------------------------------
// Kernel 1: qkv GEMM (m97 structure). Q/K scatter; V written transposed
// [B,H,D,T] with t-contiguous ushort4 stores. Unchanged from R11.
// ---------------------------------------------------------------------------
__global__ __launch_bounds__(256) void qkv_mfma(
    const unsigned short* __restrict__ xb, const unsigned short* __restrict__ Wt,
    const float* __restrict__ bias,
    unsigned short* __restrict__ Q, unsigned short* __restrict__ Kd,
    unsigned short* __restrict__ Vt)
{
    const int n0 = blockIdx.x * 128;
    const int m0 = blockIdx.y * 128;
    const int tid = threadIdx.x;
    const int lane = tid & 63;
    const int w = tid >> 6;
    const int wm = w & 1;
    const int wn = w >> 1;
    const int lm = lane & 15;
    const int lq = lane >> 4;

    __shared__ __align__(16) unsigned short As[128 * 32];
    __shared__ __align__(16) unsigned short Bs[128 * 32];

    f32x4 acc[4][4] = {};

    const int srow = lane >> 2;
    const int schunk = lane & 3;

    for (int k0 = 0; k0 < CDIM; k0 += 32) {
        __syncthreads();
#pragma unroll
        for (int c = 0; c < 2; ++c) {
            const int rbase = c * 64 + w * 16;
            async_copy16(&As[rbase * 32],
                         &xb[(size_t)(m0 + rbase + srow) * CDIM + k0 + schunk * 8]);
            async_copy16(&Bs[rbase * 32],
                         &Wt[(size_t)(n0 + rbase + srow) * CDIM + k0 + schunk * 8]);
        }
        __syncthreads();

        bf16x8 a[4], b[4];
#pragma unroll
        for (int mi = 0; mi < 4; ++mi)
            a[mi] = *(const bf16x8*)&As[(wm * 64 + mi * 16 + lm) * 32 + lq * 8];
#pragma unroll
        for (int ni = 0; ni < 4; ++ni)
            b[ni] = *(const bf16x8*)&Bs[(wn * 64 + ni * 16 + lm) * 32 + lq * 8];
#pragma unroll
        for (int mi = 0; mi < 4; ++mi)
#pragma unroll
            for (int ni = 0; ni < 4; ++ni)
                acc[mi][ni] = __builtin_amdgcn_mfma_f32_16x16x32_bf16(
                    a[mi], b[ni], acc[mi][ni], 0, 0, 0);
    }

#pragma unroll
    for (int ni = 0; ni < 4; ++ni) {
        const int gn = n0 + wn * 64 + ni * 16 + lm;
        const float bb = bias[gn];
        const int h = gn / 192;
        const int rr = gn % 192;
        const int which = rr >> 6;
        const int d = rr & 63;
        if (which == 2) {
#pragma unroll
            for (int mi = 0; mi < 4; ++mi) {
                const int gm0 = m0 + wm * 64 + mi * 16 + lq * 4;
                const int bidx = gm0 >> 10;
                const int t0 = gm0 & 1023;
                ushort4 sv;
                sv.x = f2bf(acc[mi][ni][0] + bb);
                sv.y = f2bf(acc[mi][ni][1] + bb);
                sv.z = f2bf(acc[mi][ni][2] + bb);
                sv.w = f2bf(acc[mi][ni][3] + bb);
                *(ushort4*)&Vt[(((size_t)bidx * 12 + h) * 64 + d) * TDIM + t0] = sv;
            }
        } else {
            unsigned short* dst = (which == 0) ? Q : Kd;
#pragma unroll
            for (int mi = 0; mi < 4; ++mi) {
#pragma unroll
                for (int r = 0; r < 4; ++r) {
                    const int gm = m0 + wm * 64 + mi * 16 + lq * 4 + r;
                    const int bidx = gm >> 10;
                    const int t = gm & 1023;
                    dst[(((size_t)bidx * 12 + h) * TDIM + t) * 64 + d] = f2bf(acc[mi][ni][r] + bb);
                }
            }
        }
    }
}

// ---------------------------------------------------------------------------
// Kernel 2: MFMA causal flash attention v4 — 64-query tiles paired (pi,15-pi).
// grid = (8, 96), block = 256 (4 waves); wave owns 16 queries of each tile.
// Shift-free softmax; V pre-transposed; Q frags direct from global.
// ---------------------------------------------------------------------------
#define ATTN_TILE(aq, q0t, qt_t, l_p, o) do {                                   \
    const bool diag_ = (kt == (qt_t));                                          \
    float pf[4][4];                                                             \
    _Pragma("unroll")                                                           \
    for (int nt = 0; nt < 4; ++nt) {                                            \
        f32x4 s = {};                                                           \
        _Pragma("unroll")                                                       \
        for (int kc = 0; kc < 2; ++kc) {                                        \
            bf16x8 bfrag = *(const bf16x8*)&Ks[nt * 16 + lm][kc * 32 + lq * 8]; \
            s = __builtin_amdgcn_mfma_f32_16x16x32_bf16(aq[kc], bfrag, s, 0, 0, 0); \
        }                                                                       \
        const int keyg = kbase + nt * 16 + lm;                                  \
        _Pragma("unroll")                                                       \
        for (int r = 0; r < 4; ++r) {                                           \
            float p = __builtin_amdgcn_exp2f(s[r] * SC);                        \
            if (diag_) {                                                        \
                const int qg = (q0t) + w * 16 + lq * 4 + r;                     \
                if (keyg > qg) p = 0.f;                                         \
            }                                                                   \
            pf[nt][r] = p;                                                      \
        }                                                                       \
    }                                                                           \
    _Pragma("unroll")                                                           \
    for (int r = 0; r < 4; ++r) {                                               \
        l_p[r] += pf[0][r] + pf[1][r] + pf[2][r] + pf[3][r];                    \
        _Pragma("unroll")                                                       \
        for (int nt = 0; nt < 4; ++nt)                                          \
            Ps[w][lq * 4 + r][nt * 16 + lm] = f2bf(pf[nt][r]);                  \
    }                                                                           \
    {                                                                           \
        bf16x8 ap[2];                                                           \
        _Pragma("unroll")                                                       \
        for (int kc = 0; kc < 2; ++kc)                                          \
            ap[kc] = *(const bf16x8*)&Ps[w][lm][kc * 32 + lq * 8];              \
        _Pragma("unroll")                                                       \
        for (int nt = 0; nt < 4; ++nt) {                                        \
            _Pragma("unroll")                                                   \
            for (int kc = 0; kc < 2; ++kc) {                                    \
                bf16x8 bv = *(const bf16x8*)&Vts[nt * 16 + lm][kc * 32 + lq * 8]; \
                o[nt] = __builtin_amdgcn_mfma_f32_16x16x32_bf16(ap[kc], bv, o[nt], 0, 0, 0); \
            }                                                                   \
        }                                                                       \
    }                                                                           \
} while (0)

#define ATTN_EPI(q0t, l_p, o) do {                                              \
    _Pragma("unroll")                                                           \
    for (int r = 0; r < 4; ++r) {                                               \
        float l = l_p[r];                                                       \
        _Pragma("unroll")                                                       \
        for (int off = 1; off < 16; off <<= 1) l += __shfl_xor(l, off);         \
        const float inv = 1.0f / l;                                             \
        const int qg = (q0t) + w * 16 + lq * 4 + r;                             \
        _Pragma("unroll")                                                       \
        for (int nt = 0; nt < 4; ++nt)                                          \
            Yb[(size_t)qg * 64 + nt * 16 + lm] = f2bf(o[nt][r] * inv);          \
    }                                                                           \
} while (0)

__global__ __launch_bounds__(256) void attn_mfma(
    const unsigned short* __restrict__ Q, const unsigned short* __restrict__ K,
    const unsigned short* __restrict__ Vt, unsigned short* __restrict__ Y)
{
    const int pi = blockIdx.x;        // 0..7 -> 64-query tiles (pi, 15-pi)
    const int bh = blockIdx.y;        // 0..95
    const int qtA = pi, qtB = 15 - pi;
    const int q0A = qtA * 64, q0B = qtB * 64;
    const int tid = threadIdx.x;
    const int lane = tid & 63;
    const int w = tid >> 6;
    const int lm = lane & 15;
    const int lq = lane >> 4;

    __shared__ __align__(16) unsigned short Ks[64][72];
    __shared__ __align__(16) unsigned short Vts[64][72];   // [d][key]
    __shared__ __align__(16) unsigned short Ps[4][16][72];

    const unsigned short* Qb = Q + (size_t)bh * TDIM * 64;
    const unsigned short* Kb = K + (size_t)bh * TDIM * 64;
    const unsigned short* Vtb = Vt + (size_t)bh * 64 * TDIM;
    unsigned short* Yb = Y + (size_t)bh * TDIM * 64;

    // Q fragments directly from global (once per kernel).
    bf16x8 aqA[2], aqB[2];
#pragma unroll
    for (int kc = 0; kc < 2; ++kc) {
        aqA[kc] = *(const bf16x8*)&Qb[(size_t)(q0A + w * 16 + lm) * 64 + kc * 32 + lq * 8];
        aqB[kc] = *(const bf16x8*)&Qb[(size_t)(q0B + w * 16 + lm) * 64 + kc * 32 + lq * 8];
    }

    float lA[4] = {}, lB[4] = {};
    f32x4 oA[4] = {}, oB[4] = {};

    const float SC = 0.125f * 1.44269504f;
    const int nktA = qtA + 1;         // tiles A attends: kt in [0, qtA]
    const int nktB = qtB + 1;         // = 16 - pi

    for (int kt = 0; kt < nktB; ++kt) {
        const int kbase = kt * 64;
        __syncthreads();
        // K tile rows + V^T tile rows (both vectorized 16B copies).
#pragma unroll
        for (int it = 0; it < 2; ++it) {
            const int idx = tid + it * 256;
            const int r = idx >> 3;
            const int c = idx & 7;
            *(u16x8*)&Ks[r][c * 8] =
                *(const u16x8*)&Kb[(size_t)(kbase + r) * 64 + c * 8];
            *(u16x8*)&Vts[r][c * 8] =
                *(const u16x8*)&Vtb[(size_t)r * TDIM + kbase + c * 8];
        }
        __syncthreads();

        ATTN_TILE(aqB, q0B, qtB, lB, oB);
        if (kt < nktA) ATTN_TILE(aqA, q0A, qtA, lA, oA);
    }

    ATTN_EPI(q0A, lA, oA);
    ATTN_EPI(q0B, lB, oB);
}

// ---------------------------------------------------------------------------
// Kernel 3: proj GEMM (m97 structure, unchanged from R8).
// ---------------------------------------------------------------------------
__global__ __launch_bounds__(256) void proj_mfma(
    const unsigned short* __restrict__ Y, const unsigned short* __restrict__ Wt,
    const float* __restrict__ bias, float* __restrict__ out)
{
    const int n0 = blockIdx.x * 128;
    const int m0 = blockIdx.y * 128;
    const int tid = threadIdx.x;
    const int lane = tid & 63;
    const int w = tid >> 6;
    const int wm = w & 1;
    const int wn = w >> 1;
    const int lm = lane & 15;
    const int lq = lane >> 4;

    __shared__ __align__(16) unsigned short As[128 * 32];
    __shared__ __align__(16) unsigned short Bs[128 * 32];

    f32x4 acc[4][4] = {};

    const int srow = lane >> 2;
    const int schunk = lane & 3;

    for (int k0 = 0; k0 < CDIM; k0 += 32) {
        const int h = k0 >> 6;
        const int inner = k0 & 63;
        __syncthreads();
#pragma unroll
        for (int c = 0; c < 2; ++c) {
            const int rbase = c * 64 + w * 16;
            const int m = m0 + rbase + srow;
            const int bidx = m >> 10;
            const int t = m & 1023;
            async_copy16(&As[rbase * 32],
                         &Y[(((size_t)bidx * 12 + h) * TDIM + t) * 64 + inner + schunk * 8]);
            async_copy16(&Bs[rbase * 32],
                         &Wt[(size_t)(n0 + rbase + srow) * CDIM + k0 + schunk * 8]);
        }
        __syncthreads();

        bf16x8 a[4], b[4];
#pragma unroll
        for (int mi = 0; mi < 4; ++mi)
            a[mi] = *(const bf16x8*)&As[(wm * 64 + mi * 16 + lm) * 32 + lq * 8];
#pragma unroll
        for (int ni = 0; ni < 4; ++ni)
            b[ni] = *(const bf16x8*)&Bs[(wn * 64 + ni * 16 + lm) * 32 + lq * 8];
#pragma unroll
        for (int mi = 0; mi < 4; ++mi)
#pragma unroll
            for (int ni = 0; ni < 4; ++ni)
                acc[mi][ni] = __builtin_amdgcn_mfma_f32_16x16x32_bf16(
                    a[mi], b[ni], acc[mi][ni], 0, 0, 0);
    }

#pragma unroll
    for (int ni = 0; ni < 4; ++ni) {
        const int gn = n0 + wn * 64 + ni * 16 + lm;
        const float bb = bias[gn];
#pragma unroll
        for (int mi = 0; mi < 4; ++mi) {
#pragma unroll
            for (int r = 0; r < 4; ++r) {
                const int gm = m0 + wm * 64 + mi * 16 + lq * 4 + r;
                out[(size_t)gm * CDIM + gn] = acc[mi][ni][r] + bb;
            }
        }
    }
}

extern "C" void kernel_launch(void* const* d_in, const int* in_sizes, int n_in,
                              void* d_out, int out_size, void* d_ws, size_t ws_size,
                              hipStream_t stream) {
    const float* x      = (const float*)d_in[0];
    const float* W_attn = (const float*)d_in[1];
    const float* b_attn = (const float*)d_in[2];
    const float* W_proj = (const float*)d_in[3];
    const float* b_proj = (const float*)d_in[4];
    float* out = (float*)d_out;

    const size_t per = (size_t)8 * 12 * 1024 * 64;
    unsigned short* Q   = (unsigned short*)d_ws;
    unsigned short* K   = Q + per;
    unsigned short* Vt  = K + per;   // [B,H,D,T] transposed
    unsigned short* xb  = Vt + per;
    unsigned short* Wta = xb + (size_t)8192 * CDIM;
    unsigned short* Wtp = Wta + (size_t)NDIM * CDIM;

    cast_x<<<dim3(6144), 256, 0, stream>>>(x, xb);
    transpose_cast<NDIM><<<dim3(72, 24), 256, 0, stream>>>(W_attn, Wta);
    transpose_cast<CDIM><<<dim3(24, 24), 256, 0, stream>>>(W_proj, Wtp);

    qkv_mfma<<<dim3(18, 64), 256, 0, stream>>>(xb, Wta, b_attn, Q, K, Vt);
    attn_mfma<<<dim3(8, 96), 256, 0, stream>>>(Q, K, Vt, Q);
    proj_mfma<<<dim3(6, 64), 256, 0, stream>>>(Q, Wtp, b_proj, out);
}

// Round 13
// 202.052 us; speedup vs baseline: 1.1977x; 1.0117x over previous
//
#include <hip/hip_runtime.h>
#include <hip/hip_bf16.h>

// Problem: B=8, T=1024, C=768, H=12, HD=64. M = 8192. fp32 in/out.
// R13: qkv epilogue vectorization. Each wave's 64-col group is one
// (h, which, d=0..63) slice (gn=64a+e => which=a%3, d=e). Q/K epilogue now
// round-trips through per-wave LDS (C-layout write -> row read, same-wave
// ordering validated by attn's P transform since R7) -> u16x8 global stores.
// R12 had ~43 scalar 2B stores/thread at 128B stride for Q/K columns.
// attn (R12 paired tiles) + proj + casts unchanged.

#define TDIM 1024
#define CDIM 768
#define NDIM 2304

typedef __attribute__((ext_vector_type(8))) short bf16x8;
typedef __attribute__((ext_vector_type(8))) unsigned short u16x8;
typedef __attribute__((ext_vector_type(4))) float f32x4;

__device__ __forceinline__ unsigned short f2bf(float f) {
    unsigned int u;
    __builtin_memcpy(&u, &f, 4);
    u += 0x7FFFu + ((u >> 16) & 1u);  // RNE
    return (unsigned short)(u >> 16);
}

__device__ __forceinline__ void async_copy16(void* lds, const void* g) {
    __builtin_amdgcn_global_load_lds(
        (const __attribute__((address_space(1))) void*)g,
        (__attribute__((address_space(3))) void*)lds, 16, 0, 0);
}

// ---------------------------------------------------------------------------
// Precast kernels.
// ---------------------------------------------------------------------------
__global__ __launch_bounds__(256) void cast_x(const float* __restrict__ x,
                                              unsigned short* __restrict__ xb) {
    const size_t i = ((size_t)blockIdx.x * 256 + threadIdx.x) * 4;
    float4 v = *(const float4*)&x[i];
    ushort4 s;
    s.x = f2bf(v.x); s.y = f2bf(v.y); s.z = f2bf(v.z); s.w = f2bf(v.w);
    *(ushort4*)&xb[i] = s;
}

template <int N>
__global__ __launch_bounds__(256) void transpose_cast(const float* __restrict__ W,
                                                      unsigned short* __restrict__ Wt) {
    __shared__ float tile[32][33];
    const int n0 = blockIdx.x * 32;
    const int k0 = blockIdx.y * 32;
    const int tx = threadIdx.x & 31;
    const int ty = threadIdx.x >> 5;
#pragma unroll
    for (int i = 0; i < 4; ++i)
        tile[ty + i * 8][tx] = W[(size_t)(k0 + ty + i * 8) * N + n0 + tx];
    __syncthreads();
#pragma unroll
    for (int i = 0; i < 4; ++i)
        Wt[(size_t)(n0 + ty + i * 8) * CDIM + k0 + tx] = f2bf(tile[tx][ty + i * 8]);
}

// ---------------------------------------------------------------------------
// Kernel 1: qkv GEMM (m97 structure) with vectorized epilogue.
// Q/K stored [B,H,T,64] via per-wave LDS transpose; V stored transposed
// [B,H,D,T] via direct t-contiguous ushort4 stores.
// ---------------------------------------------------------------------------
__global__ __launch_bounds__(256) void qkv_mfma(
    const unsigned short* __restrict__ xb, const unsigned short* __restrict__ Wt,
    const float* __restrict__ bias,
    unsigned short* __restrict__ Q, unsigned short* __restrict__ Kd,
    unsigned short* __restrict__ Vt)
{
    const int n0 = blockIdx.x * 128;
    const int m0 = blockIdx.y * 128;
    const int tid = threadIdx.x;
    const int lane = tid & 63;
    const int w = tid >> 6;
    const int wm = w & 1;
    const int wn = w >> 1;
    const int lm = lane & 15;
    const int lq = lane >> 4;

    __shared__ __align__(16) unsigned short As[128 * 32];
    __shared__ __align__(16) unsigned short Bs[128 * 32];
    __shared__ __align__(16) unsigned short Es[4][16][72];  // epilogue transpose

    f32x4 acc[4][4] = {};

    const int srow = lane >> 2;
    const int schunk = lane & 3;

    for (int k0 = 0; k0 < CDIM; k0 += 32) {
        __syncthreads();
#pragma unroll
        for (int c = 0; c < 2; ++c) {
            const int rbase = c * 64 + w * 16;
            async_copy16(&As[rbase * 32],
                         &xb[(size_t)(m0 + rbase + srow) * CDIM + k0 + schunk * 8]);
            async_copy16(&Bs[rbase * 32],
                         &Wt[(size_t)(n0 + rbase + srow) * CDIM + k0 + schunk * 8]);
        }
        __syncthreads();

        bf16x8 a[4], b[4];
#pragma unroll
        for (int mi = 0; mi < 4; ++mi)
            a[mi] = *(const bf16x8*)&As[(wm * 64 + mi * 16 + lm) * 32 + lq * 8];
#pragma unroll
        for (int ni = 0; ni < 4; ++ni)
            b[ni] = *(const bf16x8*)&Bs[(wn * 64 + ni * 16 + lm) * 32 + lq * 8];
#pragma unroll
        for (int mi = 0; mi < 4; ++mi)
#pragma unroll
            for (int ni = 0; ni < 4; ++ni)
                acc[mi][ni] = __builtin_amdgcn_mfma_f32_16x16x32_bf16(
                    a[mi], b[ni], acc[mi][ni], 0, 0, 0);
    }

    // Epilogue. Wave's 64-col group: a = 2*bx + wn; which = a%3; h = (n0+wn*64)/192;
    // d = ni*16+lm covers 0..63 exactly.
    const int ga = (n0 >> 6) + wn;
    const int which = ga % 3;
    const int h = (n0 + wn * 64) / 192;
    float bb[4];
#pragma unroll
    for (int ni = 0; ni < 4; ++ni)
        bb[ni] = bias[n0 + wn * 64 + ni * 16 + lm];

    if (which == 2) {
        // V transposed [B,H,D,T]: direct t-contiguous ushort4 stores.
#pragma unroll
        for (int ni = 0; ni < 4; ++ni) {
            const int d = ni * 16 + lm;
#pragma unroll
            for (int mi = 0; mi < 4; ++mi) {
                const int gm0 = m0 + wm * 64 + mi * 16 + lq * 4;
                const int bidx = gm0 >> 10;
                const int t0 = gm0 & 1023;
                ushort4 sv;
                sv.x = f2bf(acc[mi][ni][0] + bb[ni]);
                sv.y = f2bf(acc[mi][ni][1] + bb[ni]);
                sv.z = f2bf(acc[mi][ni][2] + bb[ni]);
                sv.w = f2bf(acc[mi][ni][3] + bb[ni]);
                *(ushort4*)&Vt[(((size_t)bidx * 12 + h) * 64 + d) * TDIM + t0] = sv;
            }
        }
    } else {
        // Q/K [B,H,T,64]: per-wave LDS transpose -> 16B row stores.
        unsigned short* dst = (which == 0) ? Q : Kd;
        const int erow = lane >> 2;   // 0..15
        const int ecol = lane & 3;    // 0..3 -> 16-short chunks
#pragma unroll
        for (int mi = 0; mi < 4; ++mi) {
#pragma unroll
            for (int r = 0; r < 4; ++r)
#pragma unroll
                for (int ni = 0; ni < 4; ++ni)
                    Es[w][lq * 4 + r][ni * 16 + lm] = f2bf(acc[mi][ni][r] + bb[ni]);
            // same-wave LDS write->read (in-order per wave; validated by attn P)
            const int t = m0 + wm * 64 + mi * 16 + erow;
            const int bidx = t >> 10;
            const int tt = t & 1023;
            unsigned short* drow = &dst[(((size_t)bidx * 12 + h) * TDIM + tt) * 64];
            u16x8 v0 = *(const u16x8*)&Es[w][erow][ecol * 16];
            u16x8 v1 = *(const u16x8*)&Es[w][erow][ecol * 16 + 8];
            *(u16x8*)&drow[ecol * 16] = v0;
            *(u16x8*)&drow[ecol * 16 + 8] = v1;
        }
    }
}

// ---------------------------------------------------------------------------
// Kernel 2: MFMA causal flash attention v4 (R12, verified) — 64-query tiles
// paired (pi, 15-pi); shift-free softmax; V pre-transposed; Q frags direct.
// ---------------------------------------------------------------------------
#define ATTN_TILE(aq, q0t, qt_t, l_p, o) do {                                   \
    const bool diag_ = (kt == (qt_t));                                          \
    float pf[4][4];                                                             \
    _Pragma("unroll")                                                           \
    for (int nt = 0; nt < 4; ++nt) {                                            \
        f32x4 s = {};                                                           \
        _Pragma("unroll")                                                       \
        for (int kc = 0; kc < 2; ++kc) {                                        \
            bf16x8 bfrag = *(const bf16x8*)&Ks[nt * 16 + lm][kc * 32 + lq * 8]; \
            s = __builtin_amdgcn_mfma_f32_16x16x32_bf16(aq[kc], bfrag, s, 0, 0, 0); \
        }                                                                       \
        const int keyg = kbase + nt * 16 + lm;                                  \
        _Pragma("unroll")                                                       \
        for (int r = 0; r < 4; ++r) {                                           \
            float p = __builtin_amdgcn_exp2f(s[r] * SC);                        \
            if (diag_) {                                                        \
                const int qg = (q0t) + w * 16 + lq * 4 + r;                     \
                if (keyg > qg) p = 0.f;                                         \
            }                                                                   \
            pf[nt][r] = p;                                                      \
        }                                                                       \
    }                                                                           \
    _Pragma("unroll")                                                           \
    for (int r = 0; r < 4; ++r) {                                               \
        l_p[r] += pf[0][r] + pf[1][r] + pf[2][r] + pf[3][r];                    \
        _Pragma("unroll")                                                       \
        for (int nt = 0; nt < 4; ++nt)                                          \
            Ps[w][lq * 4 + r][nt * 16 + lm] = f2bf(pf[nt][r]);                  \
    }                                                                           \
    {                                                                           \
        bf16x8 ap[2];                                                           \
        _Pragma("unroll")                                                       \
        for (int kc = 0; kc < 2; ++kc)                                          \
            ap[kc] = *(const bf16x8*)&Ps[w][lm][kc * 32 + lq * 8];              \
        _Pragma("unroll")                                                       \
        for (int nt = 0; nt < 4; ++nt) {                                        \
            _Pragma("unroll")                                                   \
            for (int kc = 0; kc < 2; ++kc) {                                    \
                bf16x8 bv = *(const bf16x8*)&Vts[nt * 16 + lm][kc * 32 + lq * 8]; \
                o[nt] = __builtin_amdgcn_mfma_f32_16x16x32_bf16(ap[kc], bv, o[nt], 0, 0, 0); \
            }                                                                   \
        }                                                                       \
    }                                                                           \
} while (0)

#define ATTN_EPI(q0t, l_p, o) do {                                              \
    _Pragma("unroll")                                                           \
    for (int r = 0; r < 4; ++r) {                                               \
        float l = l_p[r];                                                       \
        _Pragma("unroll")                                                       \
        for (int off = 1; off < 16; off <<= 1) l += __shfl_xor(l, off);         \
        const float inv = 1.0f / l;                                             \
        const int qg = (q0t) + w * 16 + lq * 4 + r;                             \
        _Pragma("unroll")                                                       \
        for (int nt = 0; nt < 4; ++nt)                                          \
            Yb[(size_t)qg * 64 + nt * 16 + lm] = f2bf(o[nt][r] * inv);          \
    }                                                                           \
} while (0)

__global__ __launch_bounds__(256) void attn_mfma(
    const unsigned short* __restrict__ Q, const unsigned short* __restrict__ K,
    const unsigned short* __restrict__ Vt, unsigned short* __restrict__ Y)
{
    const int pi = blockIdx.x;        // 0..7 -> 64-query tiles (pi, 15-pi)
    const int bh = blockIdx.y;        // 0..95
    const int qtA = pi, qtB = 15 - pi;
    const int q0A = qtA * 64, q0B = qtB * 64;
    const int tid = threadIdx.x;
    const int lane = tid & 63;
    const int w = tid >> 6;
    const int lm = lane & 15;
    const int lq = lane >> 4;

    __shared__ __align__(16) unsigned short Ks[64][72];
    __shared__ __align__(16) unsigned short Vts[64][72];   // [d][key]
    __shared__ __align__(16) unsigned short Ps[4][16][72];

    const unsigned short* Qb = Q + (size_t)bh * TDIM * 64;
    const unsigned short* Kb = K + (size_t)bh * TDIM * 64;
    const unsigned short* Vtb = Vt + (size_t)bh * 64 * TDIM;
    unsigned short* Yb = Y + (size_t)bh * TDIM * 64;

    bf16x8 aqA[2], aqB[2];
#pragma unroll
    for (int kc = 0; kc < 2; ++kc) {
        aqA[kc] = *(const bf16x8*)&Qb[(size_t)(q0A + w * 16 + lm) * 64 + kc * 32 + lq * 8];
        aqB[kc] = *(const bf16x8*)&Qb[(size_t)(q0B + w * 16 + lm) * 64 + kc * 32 + lq * 8];
    }

    float lA[4] = {}, lB[4] = {};
    f32x4 oA[4] = {}, oB[4] = {};

    const float SC = 0.125f * 1.44269504f;
    const int nktA = qtA + 1;
    const int nktB = qtB + 1;

    for (int kt = 0; kt < nktB; ++kt) {
        const int kbase = kt * 64;
        __syncthreads();
#pragma unroll
        for (int it = 0; it < 2; ++it) {
            const int idx = tid + it * 256;
            const int r = idx >> 3;
            const int c = idx & 7;
            *(u16x8*)&Ks[r][c * 8] =
                *(const u16x8*)&Kb[(size_t)(kbase + r) * 64 + c * 8];
            *(u16x8*)&Vts[r][c * 8] =
                *(const u16x8*)&Vtb[(size_t)r * TDIM + kbase + c * 8];
        }
        __syncthreads();

        ATTN_TILE(aqB, q0B, qtB, lB, oB);
        if (kt < nktA) ATTN_TILE(aqA, q0A, qtA, lA, oA);
    }

    ATTN_EPI(q0A, lA, oA);
    ATTN_EPI(q0B, lB, oB);
}

// ---------------------------------------------------------------------------
// Kernel 3: proj GEMM (m97 structure, unchanged from R8).
// ---------------------------------------------------------------------------
__global__ __launch_bounds__(256) void proj_mfma(
    const unsigned short* __restrict__ Y, const unsigned short* __restrict__ Wt,
    const float* __restrict__ bias, float* __restrict__ out)
{
    const int n0 = blockIdx.x * 128;
    const int m0 = blockIdx.y * 128;
    const int tid = threadIdx.x;
    const int lane = tid & 63;
    const int w = tid >> 6;
    const int wm = w & 1;
    const int wn = w >> 1;
    const int lm = lane & 15;
    const int lq = lane >> 4;

    __shared__ __align__(16) unsigned short As[128 * 32];
    __shared__ __align__(16) unsigned short Bs[128 * 32];

    f32x4 acc[4][4] = {};

    const int srow = lane >> 2;
    const int schunk = lane & 3;

    for (int k0 = 0; k0 < CDIM; k0 += 32) {
        const int h = k0 >> 6;
        const int inner = k0 & 63;
        __syncthreads();
#pragma unroll
        for (int c = 0; c < 2; ++c) {
            const int rbase = c * 64 + w * 16;
            const int m = m0 + rbase + srow;
            const int bidx = m >> 10;
            const int t = m & 1023;
            async_copy16(&As[rbase * 32],
                         &Y[(((size_t)bidx * 12 + h) * TDIM + t) * 64 + inner + schunk * 8]);
            async_copy16(&Bs[rbase * 32],
                         &Wt[(size_t)(n0 + rbase + srow) * CDIM + k0 + schunk * 8]);
        }
        __syncthreads();

        bf16x8 a[4], b[4];
#pragma unroll
        for (int mi = 0; mi < 4; ++mi)
            a[mi] = *(const bf16x8*)&As[(wm * 64 + mi * 16 + lm) * 32 + lq * 8];
#pragma unroll
        for (int ni = 0; ni < 4; ++ni)
            b[ni] = *(const bf16x8*)&Bs[(wn * 64 + ni * 16 + lm) * 32 + lq * 8];
#pragma unroll
        for (int mi = 0; mi < 4; ++mi)
#pragma unroll
            for (int ni = 0; ni < 4; ++ni)
                acc[mi][ni] = __builtin_amdgcn_mfma_f32_16x16x32_bf16(
                    a[mi], b[ni], acc[mi][ni], 0, 0, 0);
    }

#pragma unroll
    for (int ni = 0; ni < 4; ++ni) {
        const int gn = n0 + wn * 64 + ni * 16 + lm;
        const float bb = bias[gn];
#pragma unroll
        for (int mi = 0; mi < 4; ++mi) {
#pragma unroll
            for (int r = 0; r < 4; ++r) {
                const int gm = m0 + wm * 64 + mi * 16 + lq * 4 + r;
                out[(size_t)gm * CDIM + gn] = acc[mi][ni][r] + bb;
            }
        }
    }
}

extern "C" void kernel_launch(void* const* d_in, const int* in_sizes, int n_in,
                              void* d_out, int out_size, void* d_ws, size_t ws_size,
                              hipStream_t stream) {
    const float* x      = (const float*)d_in[0];
    const float* W_attn = (const float*)d_in[1];
    const float* b_attn = (const float*)d_in[2];
    const float* W_proj = (const float*)d_in[3];
    const float* b_proj = (const float*)d_in[4];
    float* out = (float*)d_out;

    const size_t per = (size_t)8 * 12 * 1024 * 64;
    unsigned short* Q   = (unsigned short*)d_ws;
    unsigned short* K   = Q + per;
    unsigned short* Vt  = K + per;   // [B,H,D,T] transposed
    unsigned short* xb  = Vt + per;
    unsigned short* Wta = xb + (size_t)8192 * CDIM;
    unsigned short* Wtp = Wta + (size_t)NDIM * CDIM;

    cast_x<<<dim3(6144), 256, 0, stream>>>(x, xb);
    transpose_cast<NDIM><<<dim3(72, 24), 256, 0, stream>>>(W_attn, Wta);
    transpose_cast<CDIM><<<dim3(24, 24), 256, 0, stream>>>(W_proj, Wtp);

    qkv_mfma<<<dim3(18, 64), 256, 0, stream>>>(xb, Wta, b_attn, Q, K, Vt);
    attn_mfma<<<dim3(8, 96), 256, 0, stream>>>(Q, K, Vt, Q);
    proj_mfma<<<dim3(6, 64), 256, 0, stream>>>(Q, Wtp, b_proj, out);
}